// Round 2
// baseline (1794.452 us; speedup 1.0000x reference)
//
#include <hip/hip_runtime.h>
#include <math.h>

// Fused WaveNet-ish encoder, v2: wave-per-o-group mapping.
//  - wave w (of 16) owns output channels o0 = 16w .. 16w+15
//  - lane owns time steps t0 = 2*lane, t0+1
//  - weights are wave-uniform -> scalar (SGPR) loads, no VALU/VMEM cost
//  - all LDS traffic is lane-contiguous ds_read/write_b64 (conflict-free)
//  - h[256][128] fp32 resident in LDS; skip kept in registers

#define BATCH 256
#define INCH  1024
#define HID   256
#define TLEN  128
#define CTXN  16
#define LEAKF 0.2f
#define EPSF  1e-8f

#define HSH_F (HID * TLEN)   // 32768 floats
#define SCR_F (16 * TLEN)    // 2048 floats
#define LDS_FLOATS (HSH_F + SCR_F + TLEN + TLEN + 16)

template<int D>
__device__ __forceinline__ void conv_layer(const float* __restrict__ cw,
                                           const float* __restrict__ cb,
                                           float* __restrict__ hsh,
                                           float* __restrict__ scr,
                                           float* __restrict__ invn,
                                           float2* acc, float2* skip,
                                           int o0, int t0, int tid)
{
    #pragma unroll
    for (int j = 0; j < 16; ++j) {
        const float bb = cb[o0 + j];
        acc[j].x = bb; acc[j].y = bb;
    }
    #pragma unroll 1
    for (int i = 0; i < HID; i += 2) {
        const float* hr0 = hsh + i * TLEN + t0;
        const float* hr1 = hr0 + TLEN;
        const float2 a0 = *(const float2*)(hr0);
        const float2 a1 = *(const float2*)(hr1);
        float2 s0, s1;
        if (D == 1) {
            const bool ok = (t0 + 2) < TLEN;            // lane-varying
            const float2 n0 = *(const float2*)(hr0 + 2); // may read next row; masked
            const float2 n1 = *(const float2*)(hr1 + 2);
            s0.x = a0.y; s0.y = ok ? n0.x : 0.f;
            s1.x = a1.y; s1.y = ok ? n1.x : 0.f;
        } else {
            const bool ok = (t0 + D) < TLEN;            // both comps valid iff true
            const float2 n0 = *(const float2*)(hr0 + D);
            const float2 n1 = *(const float2*)(hr1 + D);
            s0.x = ok ? n0.x : 0.f; s0.y = ok ? n0.y : 0.f;
            s1.x = ok ? n1.x : 0.f; s1.y = ok ? n1.y : 0.f;
        }
        const float* wp = cw + (size_t)o0 * (HID * 2) + i * 2;  // wave-uniform
        #pragma unroll
        for (int j = 0; j < 16; ++j) {
            const float4 w = *(const float4*)(wp + (size_t)j * (HID * 2)); // s_load
            acc[j].x = fmaf(w.x, a0.x, acc[j].x);
            acc[j].y = fmaf(w.x, a0.y, acc[j].y);
            acc[j].x = fmaf(w.y, s0.x, acc[j].x);
            acc[j].y = fmaf(w.y, s0.y, acc[j].y);
            acc[j].x = fmaf(w.z, a1.x, acc[j].x);
            acc[j].y = fmaf(w.z, a1.y, acc[j].y);
            acc[j].x = fmaf(w.w, s1.x, acc[j].x);
            acc[j].y = fmaf(w.w, s1.y, acc[j].y);
        }
    }
    // leaky relu + residual + per-t sumsq partials
    float ps0 = 0.f, ps1 = 0.f;
    #pragma unroll
    for (int j = 0; j < 16; ++j) {
        float yx = acc[j].x; yx = yx > 0.f ? yx : LEAKF * yx;
        float yy = acc[j].y; yy = yy > 0.f ? yy : LEAKF * yy;
        const float vx = yx + skip[j].x;
        const float vy = yy + skip[j].y;
        acc[j].x = vx; acc[j].y = vy;
        ps0 = fmaf(vx, vx, ps0);
        ps1 = fmaf(vy, vy, ps1);
    }
    *(float2*)(scr + (o0 >> 4) * TLEN + t0) = make_float2(ps0, ps1);
    __syncthreads();            // also guarantees all hsh reads above are done
    if (tid < TLEN) {
        float s = 0.f;
        #pragma unroll
        for (int g = 0; g < 16; ++g) s += scr[g * TLEN + tid];
        invn[tid] = 1.f / (sqrtf(s) + EPSF);
    }
    __syncthreads();
    const float2 iv = *(const float2*)(invn + t0);
    #pragma unroll
    for (int j = 0; j < 16; ++j) {
        const float2 v = make_float2(acc[j].x * iv.x, acc[j].y * iv.y);
        skip[j] = v;
        *(float2*)(hsh + (o0 + j) * TLEN + t0) = v;
    }
    __syncthreads();
}

__global__ __launch_bounds__(1024, 4)
void wavenet2(const float* __restrict__ x,
              const float* __restrict__ proj_w,
              const float* __restrict__ proj_b,
              const float* __restrict__ conv_w,
              const float* __restrict__ conv_b,
              const float* __restrict__ ev_w,
              const float* __restrict__ ev_b,
              const float* __restrict__ sw_w,
              const float* __restrict__ sw_b,
              float* __restrict__ out)
{
    extern __shared__ float lds[];
    float* hsh  = lds;                 // [256][128] fp32
    float* scr  = lds + HSH_F;         // [16][128] partials / colv / head partials
    float* invn = scr + SCR_F;         // [128]
    float* attn = invn + TLEN;         // [128]
    float* redf = attn + TLEN;         // [16]

    const int b    = blockIdx.x;
    const int tid  = threadIdx.x;
    const int lane = tid & 63;
    const int wv   = __builtin_amdgcn_readfirstlane(tid >> 6);  // 0..15, uniform
    const int o0   = wv << 4;
    const int t0   = lane << 1;

    float2 acc[16], skip[16];

    // ---------------- 1x1 projection 1024 -> 256 ----------------
    #pragma unroll
    for (int j = 0; j < 16; ++j) {
        const float pb = proj_b[o0 + j];
        acc[j].x = pb; acc[j].y = pb;
    }
    const float* xb = x + (size_t)b * INCH * TLEN;
    #pragma unroll 1
    for (int c = 0; c < 16; ++c) {
        // stage 64 input rows (32 KB) into LDS, aliasing the not-yet-written hsh
        const float4* src = (const float4*)(xb + (size_t)c * 64 * TLEN);
        float4* dst = (float4*)lds;
        dst[tid]        = src[tid];
        dst[tid + 1024] = src[tid + 1024];
        __syncthreads();
        #pragma unroll 1
        for (int ii = 0; ii < 64; ii += 4) {
            const float2 xr0 = *(const float2*)(lds + (ii + 0) * TLEN + t0);
            const float2 xr1 = *(const float2*)(lds + (ii + 1) * TLEN + t0);
            const float2 xr2 = *(const float2*)(lds + (ii + 2) * TLEN + t0);
            const float2 xr3 = *(const float2*)(lds + (ii + 3) * TLEN + t0);
            const float* wp = proj_w + (size_t)o0 * INCH + c * 64 + ii; // uniform
            #pragma unroll
            for (int j = 0; j < 16; ++j) {
                const float4 w = *(const float4*)(wp + (size_t)j * INCH); // s_load
                acc[j].x = fmaf(w.x, xr0.x, acc[j].x);
                acc[j].y = fmaf(w.x, xr0.y, acc[j].y);
                acc[j].x = fmaf(w.y, xr1.x, acc[j].x);
                acc[j].y = fmaf(w.y, xr1.y, acc[j].y);
                acc[j].x = fmaf(w.z, xr2.x, acc[j].x);
                acc[j].y = fmaf(w.z, xr2.y, acc[j].y);
                acc[j].x = fmaf(w.w, xr3.x, acc[j].x);
                acc[j].y = fmaf(w.w, xr3.y, acc[j].y);
            }
        }
        __syncthreads();
    }
    #pragma unroll
    for (int j = 0; j < 16; ++j) {
        skip[j] = acc[j];
        *(float2*)(hsh + (o0 + j) * TLEN + t0) = acc[j];
    }
    __syncthreads();

    // ---------------- 8 dilated residual layers ----------------
    const size_t LW = (size_t)HID * HID * 2;
    conv_layer<1 >(conv_w + 0 * LW, conv_b + 0 * HID, hsh, scr, invn, acc, skip, o0, t0, tid);
    conv_layer<2 >(conv_w + 1 * LW, conv_b + 1 * HID, hsh, scr, invn, acc, skip, o0, t0, tid);
    conv_layer<4 >(conv_w + 2 * LW, conv_b + 2 * HID, hsh, scr, invn, acc, skip, o0, t0, tid);
    conv_layer<8 >(conv_w + 3 * LW, conv_b + 3 * HID, hsh, scr, invn, acc, skip, o0, t0, tid);
    conv_layer<16>(conv_w + 4 * LW, conv_b + 4 * HID, hsh, scr, invn, acc, skip, o0, t0, tid);
    conv_layer<32>(conv_w + 5 * LW, conv_b + 5 * HID, hsh, scr, invn, acc, skip, o0, t0, tid);
    conv_layer<64>(conv_w + 6 * LW, conv_b + 6 * HID, hsh, scr, invn, acc, skip, o0, t0, tid);
    conv_layer<1 >(conv_w + 7 * LW, conv_b + 7 * HID, hsh, scr, invn, acc, skip, o0, t0, tid);

    // ---------------- switch head -> relu -> argmax ----------------
    {
        const int g8 = tid >> 7;          // 0..7 (32-channel slice)
        const int t  = tid & 127;
        float s = 0.f;
        #pragma unroll 1
        for (int o = g8 * 32; o < g8 * 32 + 32; ++o)
            s = fmaf(sw_w[o], hsh[o * TLEN + t], s);
        scr[tid] = s;
    }
    __syncthreads();
    if (tid < TLEN) {
        float s = sw_b[0];
        #pragma unroll
        for (int g = 0; g < 8; ++g) s += scr[tid + g * TLEN];
        attn[tid] = fmaxf(s, 0.f);
    }
    __syncthreads();
    if (tid < 64) {
        float v = attn[lane]; int bi = lane;
        const float v2 = attn[lane + 64];
        if (v2 > v) { v = v2; bi = lane + 64; }
        #pragma unroll
        for (int off = 32; off > 0; off >>= 1) {
            const float ov = __shfl_down(v, off);
            const int   oi = __shfl_down(bi, off);
            if (ov > v || (ov == v && oi < bi)) { v = ov; bi = oi; }
        }
        if (lane == 0) { redf[0] = v; ((int*)redf)[1] = bi; }
    }
    __syncthreads();
    const float bestv = redf[0];
    const int   bidx  = ((const int*)redf)[1];

    // gather the h column at bidx once (one-time bank conflicts, negligible)
    if (tid < HID) scr[tid] = hsh[tid * TLEN + bidx];
    __syncthreads();

    // event head: wave wv computes ctx=wv
    {
        float s = 0.f;
        #pragma unroll
        for (int q = 0; q < 4; ++q) {
            const int o = lane + 64 * q;
            s = fmaf(ev_w[wv * HID + o], scr[o], s);
        }
        #pragma unroll
        for (int off = 32; off > 0; off >>= 1) s += __shfl_down(s, off);
        if (lane == 0) out[b * CTXN + wv] = s + ev_b[wv];
    }
    // scheduling one-hot
    if (tid < TLEN) out[BATCH * CTXN + b * TLEN + tid] = (tid == bidx) ? bestv : 0.f;
}

extern "C" void kernel_launch(void* const* d_in, const int* in_sizes, int n_in,
                              void* d_out, int out_size, void* d_ws, size_t ws_size,
                              hipStream_t stream) {
    const float* x      = (const float*)d_in[0];
    const float* proj_w = (const float*)d_in[1];
    const float* proj_b = (const float*)d_in[2];
    const float* conv_w = (const float*)d_in[3];
    const float* conv_b = (const float*)d_in[4];
    const float* ev_w   = (const float*)d_in[5];
    const float* ev_b   = (const float*)d_in[6];
    const float* sw_w   = (const float*)d_in[7];
    const float* sw_b   = (const float*)d_in[8];
    float* out = (float*)d_out;

    const size_t smem = (size_t)LDS_FLOATS * sizeof(float);  // ~137 KiB
    (void)hipFuncSetAttribute((const void*)wavenet2,
                              hipFuncAttributeMaxDynamicSharedMemorySize, (int)smem);
    wavenet2<<<BATCH, 1024, smem, stream>>>(x, proj_w, proj_b, conv_w, conv_b,
                                            ev_w, ev_b, sw_w, sw_b, out);
}

// Round 4
// 601.267 us; speedup vs baseline: 2.9844x; 2.9844x over previous
//
#include <hip/hip_runtime.h>
#include <math.h>

// Fused WaveNet-ish encoder, v4: split-precision fp16 MFMA (hi + lo*2^10).
// C = A_hi*B_hi; Ccorr = A_hi*B_lo' + A_lo'*B_hi; y = C + Ccorr*2^-10.
// Wave tile 2m x 4n (32 o x 64 t). h stored in LDS as two f16 arrays (hi, lo').

#define BATCH 256
#define INCH  1024
#define HID   256
#define TLEN  128
#define CTXN  16
#define NLAY  8
#define LEAKF 0.2f
#define EPSF  1e-8f
#define SLO   0.0009765625f   // 2^-10
#define SHI   1024.0f         // 2^10

typedef _Float16 f16;
typedef f16 f16x4 __attribute__((ext_vector_type(4)));
typedef f16 f16x8 __attribute__((ext_vector_type(8)));
typedef float f32x4 __attribute__((ext_vector_type(4)));

#define HT_STRIDE 264                    // f16 per row (528 B, 16B-aligned)
#define HT_HALFS  (TLEN * HT_STRIDE)     // 33792
#define WS_CONV (NLAY*HID*2*HID)         // 1048576 halfs
#define WS_PROJ (HID*INCH)               // 262144 halfs
#define WS_TOT  (WS_CONV + WS_PROJ)      // 1310720 halfs per (hi|lo) array
#define LDS_BYTES (HT_HALFS*2*2 + (1024 + 128 + 128 + 16)*4)  // 140352

__global__ __launch_bounds__(256)
void prep_weights(const float* __restrict__ conv_w,
                  const float* __restrict__ proj_w,
                  f16* __restrict__ wh, f16* __restrict__ wlo)
{
    const int i = blockIdx.x * blockDim.x + threadIdx.x;
    if (i >= WS_TOT) return;
    float v; int dst;
    if (i < WS_CONV) {
        // src conv_w[l][o][ii][kk] -> dst [l][o][kk][ii]
        const int kk = i & 1, ii = (i >> 1) & (HID-1), o = (i >> 9) & (HID-1), l = i >> 17;
        v = conv_w[i];
        dst = ((l*HID + o)*2 + kk)*HID + ii;
    } else {
        v = proj_w[i - WS_CONV];
        dst = i;                         // [o][i] identity after conv region
    }
    const f16 hi = (f16)v;
    wh[dst]  = hi;
    wlo[dst] = (f16)((v - (float)hi) * SHI);
}

__global__ __launch_bounds__(1024, 4)
void wavenet4(const float* __restrict__ x,
              const f16*   __restrict__ wh,
              const f16*   __restrict__ wlo,
              const float* __restrict__ proj_b,
              const float* __restrict__ conv_b,
              const float* __restrict__ ev_w,
              const float* __restrict__ ev_b,
              const float* __restrict__ sw_w,
              const float* __restrict__ sw_b,
              float* __restrict__ out)
{
    extern __shared__ char ldsb[];
    f16*   Ht   = (f16*)ldsb;                      // hi  [128][264]
    f16*   Hl   = Ht + HT_HALFS;                   // lo' [128][264]
    float* scr  = (float*)(ldsb + HT_HALFS*2*2);   // [8][128]
    float* invn = scr + 1024;                      // [128]
    float* attn = invn + 128;                      // [128]
    float* redf = attn + 128;                      // [16]

    const int b    = blockIdx.x;
    const int tid  = threadIdx.x;
    const int lane = tid & 63;
    const int wv   = __builtin_amdgcn_readfirstlane(tid >> 6);  // 0..15
    const int mg   = wv & 7;           // o-range mg*32 .. +31 (2 m-tiles)
    const int ng   = wv >> 3;          // t-range ng*64 .. +63 (4 n-tiles)
    const int ob   = mg << 5;
    const int tb   = ng << 6;
    const int tcol = lane & 15;
    const int quad = lane >> 4;
    const int kk   = quad >> 1;        // conv tap
    const int ihalf= quad & 1;

    f32x4 C[2][4], Cc[2][4];
    const f16x8 z8 = (f16x8)(f16)0.f;

    // ================= 1x1 projection 1024 -> 256 =================
    #pragma unroll
    for (int mi = 0; mi < 2; ++mi) {
        const float4 bb = *(const float4*)(proj_b + ob + mi*16 + quad*4);
        const f32x4 cv = {bb.x, bb.y, bb.z, bb.w};
        #pragma unroll
        for (int nti = 0; nti < 4; ++nti) { C[mi][nti] = cv; Cc[mi][nti] = (f32x4)0.f; }
    }
    const f16* ph  = wh  + WS_CONV;    // proj hi [256][1024]
    const f16* pl  = wlo + WS_CONV;
    const float* xb = x + (size_t)b * INCH * TLEN;
    #pragma unroll 1
    for (int c = 0; c < 4; ++c) {
        __syncthreads();
        {   // stage x[c*256 .. +255][:] transposed as hi/lo f16
            const int r = tid >> 2, tq = tid & 3;
            const float* xr = xb + (size_t)(c*256 + r) * TLEN + tq*32;
            #pragma unroll
            for (int u = 0; u < 8; ++u) {
                const float4 v = *(const float4*)(xr + u*4);
                const int t = tq*32 + u*4;
                const float vv[4] = {v.x, v.y, v.z, v.w};
                #pragma unroll
                for (int e = 0; e < 4; ++e) {
                    const f16 hi = (f16)vv[e];
                    Ht[(t+e)*HT_STRIDE + r] = hi;
                    Hl[(t+e)*HT_STRIDE + r] = (f16)((vv[e] - (float)hi) * SHI);
                }
            }
        }
        __syncthreads();
        #pragma unroll 2
        for (int kb = 0; kb < 8; ++kb) {
            const int i0 = kb*32;
            f16x8 Ah[2], Al[2];
            #pragma unroll
            for (int mi = 0; mi < 2; ++mi) {
                const size_t ao = (size_t)(ob + mi*16 + tcol)*INCH + c*256 + i0 + quad*8;
                Ah[mi] = *(const f16x8*)(ph + ao);
                Al[mi] = *(const f16x8*)(pl + ao);
            }
            #pragma unroll
            for (int nti = 0; nti < 4; ++nti) {
                const int boff = (tb + nti*16 + tcol)*HT_STRIDE + i0 + quad*8;
                const f16x8 Bh = *(const f16x8*)(Ht + boff);
                const f16x8 Bl = *(const f16x8*)(Hl + boff);
                #pragma unroll
                for (int mi = 0; mi < 2; ++mi) {
                    C [mi][nti] = __builtin_amdgcn_mfma_f32_16x16x32_f16(Ah[mi], Bh, C [mi][nti], 0,0,0);
                    Cc[mi][nti] = __builtin_amdgcn_mfma_f32_16x16x32_f16(Ah[mi], Bl, Cc[mi][nti], 0,0,0);
                    Cc[mi][nti] = __builtin_amdgcn_mfma_f32_16x16x32_f16(Al[mi], Bh, Cc[mi][nti], 0,0,0);
                }
            }
        }
    }
    __syncthreads();
    #pragma unroll
    for (int mi = 0; mi < 2; ++mi) {
        #pragma unroll
        for (int nti = 0; nti < 4; ++nti) {
            const int t = tb + nti*16 + tcol;
            const int o = ob + mi*16 + quad*4;
            f16x4 h4, l4;
            #pragma unroll
            for (int r = 0; r < 4; ++r) {
                const float v = C[mi][nti][r] + Cc[mi][nti][r]*SLO;
                const f16 hi = (f16)v;
                h4[r] = hi; l4[r] = (f16)((v - (float)hi) * SHI);
            }
            *(f16x4*)(Ht + t*HT_STRIDE + o) = h4;
            *(f16x4*)(Hl + t*HT_STRIDE + o) = l4;
        }
    }
    __syncthreads();

    // ================= 8 dilated residual layers =================
    const int DIL[NLAY] = {1, 2, 4, 8, 16, 32, 64, 1};
    #pragma unroll 1
    for (int l = 0; l < NLAY; ++l) {
        const int d = DIL[l];
        #pragma unroll
        for (int mi = 0; mi < 2; ++mi) {
            const float4 bb = *(const float4*)(conv_b + l*HID + ob + mi*16 + quad*4);
            const f32x4 cv = {bb.x, bb.y, bb.z, bb.w};
            #pragma unroll
            for (int nti = 0; nti < 4; ++nti) { C[mi][nti] = cv; Cc[mi][nti] = (f32x4)0.f; }
        }
        int  bofs[4]; bool oobv[4], anym[4];
        #pragma unroll
        for (int nti = 0; nti < 4; ++nti) {
            const int row = tb + nti*16 + tcol + kk*d;
            oobv[nti] = row >= TLEN;
            anym[nti] = (tb + nti*16 + 15 + d) >= TLEN;
            bofs[nti] = (oobv[nti] ? TLEN-1 : row)*HT_STRIDE + ihalf*8;
        }
        const f16* wA = wh  + (size_t)l*HID*2*HID;
        const f16* wB = wlo + (size_t)l*HID*2*HID;
        #pragma unroll 2
        for (int kb = 0; kb < 16; ++kb) {
            const int i0 = kb*16;
            f16x8 Ah[2], Al[2];
            #pragma unroll
            for (int mi = 0; mi < 2; ++mi) {
                const size_t ao = (size_t)((ob + mi*16 + tcol)*2 + kk)*HID + i0 + ihalf*8;
                Ah[mi] = *(const f16x8*)(wA + ao);
                Al[mi] = *(const f16x8*)(wB + ao);
            }
            #pragma unroll
            for (int nti = 0; nti < 4; ++nti) {
                f16x8 Bh = *(const f16x8*)(Ht + bofs[nti] + i0);
                f16x8 Bl = *(const f16x8*)(Hl + bofs[nti] + i0);
                if (anym[nti] && oobv[nti]) { Bh = z8; Bl = z8; }
                #pragma unroll
                for (int mi = 0; mi < 2; ++mi) {
                    C [mi][nti] = __builtin_amdgcn_mfma_f32_16x16x32_f16(Ah[mi], Bh, C [mi][nti], 0,0,0);
                    Cc[mi][nti] = __builtin_amdgcn_mfma_f32_16x16x32_f16(Ah[mi], Bl, Cc[mi][nti], 0,0,0);
                    Cc[mi][nti] = __builtin_amdgcn_mfma_f32_16x16x32_f16(Al[mi], Bh, Cc[mi][nti], 0,0,0);
                }
            }
        }
        // leaky relu + residual (skip from LDS) + per-t sumsq
        float ps[4] = {0.f, 0.f, 0.f, 0.f};
        #pragma unroll
        for (int mi = 0; mi < 2; ++mi) {
            #pragma unroll
            for (int nti = 0; nti < 4; ++nti) {
                const int t = tb + nti*16 + tcol;
                const int o = ob + mi*16 + quad*4;
                const f16x4 sh = *(const f16x4*)(Ht + t*HT_STRIDE + o);
                const f16x4 sl = *(const f16x4*)(Hl + t*HT_STRIDE + o);
                #pragma unroll
                for (int r = 0; r < 4; ++r) {
                    float y = C[mi][nti][r] + Cc[mi][nti][r]*SLO;
                    y = y > 0.f ? y : LEAKF * y;
                    const float v = y + (float)sh[r] + (float)sl[r]*SLO;
                    C[mi][nti][r] = v;
                    ps[nti] = fmaf(v, v, ps[nti]);
                }
            }
        }
        #pragma unroll
        for (int nti = 0; nti < 4; ++nti) {
            ps[nti] += __shfl_xor(ps[nti], 16);
            ps[nti] += __shfl_xor(ps[nti], 32);
        }
        if (quad == 0) {
            #pragma unroll
            for (int nti = 0; nti < 4; ++nti)
                scr[mg*128 + tb + nti*16 + tcol] = ps[nti];
        }
        __syncthreads();
        if (tid < TLEN) {
            float s = 0.f;
            #pragma unroll
            for (int g = 0; g < 8; ++g) s += scr[g*128 + tid];
            invn[tid] = 1.f / (sqrtf(s) + EPSF);
        }
        __syncthreads();
        #pragma unroll
        for (int mi = 0; mi < 2; ++mi) {
            #pragma unroll
            for (int nti = 0; nti < 4; ++nti) {
                const int t = tb + nti*16 + tcol;
                const int o = ob + mi*16 + quad*4;
                const float iv = invn[t];
                f16x4 h4, l4;
                #pragma unroll
                for (int r = 0; r < 4; ++r) {
                    const float v = C[mi][nti][r] * iv;
                    const f16 hi = (f16)v;
                    h4[r] = hi; l4[r] = (f16)((v - (float)hi) * SHI);
                }
                *(f16x4*)(Ht + t*HT_STRIDE + o) = h4;
                *(f16x4*)(Hl + t*HT_STRIDE + o) = l4;
            }
        }
        __syncthreads();
    }

    // ================= switch head -> relu -> argmax =================
    {
        const int t = tid & 127, og = tid >> 7;
        const f16* hp = Ht + t*HT_STRIDE + og*32;
        const f16* lp = Hl + t*HT_STRIDE + og*32;
        float s = 0.f;
        #pragma unroll
        for (int q = 0; q < 4; ++q) {
            const f16x8 hv = *(const f16x8*)(hp + q*8);
            const f16x8 lv = *(const f16x8*)(lp + q*8);
            const float* swp = sw_w + og*32 + q*8;
            #pragma unroll
            for (int j = 0; j < 8; ++j)
                s = fmaf(swp[j], (float)hv[j] + (float)lv[j]*SLO, s);
        }
        scr[og*128 + t] = s;
    }
    __syncthreads();
    if (tid < TLEN) {
        float s = sw_b[0];
        #pragma unroll
        for (int g = 0; g < 8; ++g) s += scr[g*128 + tid];
        attn[tid] = fmaxf(s, 0.f);
    }
    __syncthreads();
    if (tid < 64) {
        float v = attn[lane]; int bi = lane;
        const float v2 = attn[lane + 64];
        if (v2 > v) { v = v2; bi = lane + 64; }
        #pragma unroll
        for (int off = 32; off > 0; off >>= 1) {
            const float ov = __shfl_down(v, off);
            const int   oi = __shfl_down(bi, off);
            if (ov > v || (ov == v && oi < bi)) { v = ov; bi = oi; }
        }
        if (lane == 0) { redf[0] = v; ((int*)redf)[1] = bi; }
    }
    __syncthreads();
    const float bestv = redf[0];
    const int   bidx  = ((const int*)redf)[1];

    // event head: wave wv computes ctx=wv from h[:, bidx]
    {
        float s = 0.f;
        #pragma unroll
        for (int q = 0; q < 4; ++q) {
            const int o = lane + 64*q;
            const float hv = (float)Ht[bidx*HT_STRIDE + o] + (float)Hl[bidx*HT_STRIDE + o]*SLO;
            s = fmaf(ev_w[wv*HID + o], hv, s);
        }
        #pragma unroll
        for (int off = 32; off > 0; off >>= 1) s += __shfl_down(s, off);
        if (lane == 0) out[b*CTXN + wv] = s + ev_b[wv];
    }
    if (tid < TLEN) out[BATCH*CTXN + b*TLEN + tid] = (tid == bidx) ? bestv : 0.f;
}

extern "C" void kernel_launch(void* const* d_in, const int* in_sizes, int n_in,
                              void* d_out, int out_size, void* d_ws, size_t ws_size,
                              hipStream_t stream) {
    const float* x      = (const float*)d_in[0];
    const float* proj_w = (const float*)d_in[1];
    const float* proj_b = (const float*)d_in[2];
    const float* conv_w = (const float*)d_in[3];
    const float* conv_b = (const float*)d_in[4];
    const float* ev_w   = (const float*)d_in[5];
    const float* ev_b   = (const float*)d_in[6];
    const float* sw_w   = (const float*)d_in[7];
    const float* sw_b   = (const float*)d_in[8];
    float* out = (float*)d_out;

    f16* wh  = (f16*)d_ws;            // WS_TOT halfs
    f16* wlo = wh + WS_TOT;           // WS_TOT halfs (5 MB total)

    prep_weights<<<(WS_TOT + 255)/256, 256, 0, stream>>>(conv_w, proj_w, wh, wlo);

    (void)hipFuncSetAttribute((const void*)wavenet4,
                              hipFuncAttributeMaxDynamicSharedMemorySize, (int)LDS_BYTES);
    wavenet4<<<BATCH, 1024, LDS_BYTES, stream>>>(x, wh, wlo, proj_b, conv_b,
                                                 ev_w, ev_b, sw_w, sw_b, out);
}

// Round 5
// 595.502 us; speedup vs baseline: 3.0133x; 1.0097x over previous
//
#include <hip/hip_runtime.h>
#include <math.h>

// Fused WaveNet-ish encoder, v5: 32x32x16 f16 MFMA, split-precision hi/lo.
// - wave tile 32o x 64t (8 mg x 2 ng), accum f32x16 x2 (+correction x2)
// - Ht/Hl rows XOR-swizzled at 8-half granularity to break bank conflicts
// - 2 barriers per layer (redundant per-lane invn from scr)
// - projection: register-prefetch next x-chunk during GEMM (HBM/MFMA overlap)

#define BATCH 256
#define INCH  1024
#define HID   256
#define TLEN  128
#define CTXN  16
#define NLAY  8
#define LEAKF 0.2f
#define EPSF  1e-8f
#define SLO   0.0009765625f   // 2^-10
#define SHI   1024.0f         // 2^10

typedef _Float16 f16;
typedef f16 f16x4 __attribute__((ext_vector_type(4)));
typedef f16 f16x8 __attribute__((ext_vector_type(8)));
typedef float f32x16 __attribute__((ext_vector_type(16)));

#define HT_STRIDE 264                    // halfs per row (528B, rows 16B-aligned)
#define HT_HALFS  (TLEN * HT_STRIDE)     // 33792
#define SCR_STRIDE 132
#define WS_CONV (NLAY*HID*2*HID)
#define WS_PROJ (HID*INCH)
#define WS_TOT  (WS_CONV + WS_PROJ)
#define LDS_BYTES (HT_HALFS*2*2 + (8*SCR_STRIDE + TLEN + 16)*4)   // 139968

#define MFMA32(A,B,C) __builtin_amdgcn_mfma_f32_32x32x16_f16(A,B,C,0,0,0)
#define SW(t) ((((t)>>3)&3)<<3)

__global__ __launch_bounds__(256)
void prep_weights(const float* __restrict__ conv_w,
                  const float* __restrict__ proj_w,
                  f16* __restrict__ wh, f16* __restrict__ wlo)
{
    const int i = blockIdx.x * blockDim.x + threadIdx.x;
    if (i >= WS_TOT) return;
    float v; int dst;
    if (i < WS_CONV) {
        // src conv_w[l][o][ii][kk] -> dst [l][o][kk][ii]
        const int kk = i & 1, ii = (i >> 1) & (HID-1), o = (i >> 9) & (HID-1), l = i >> 17;
        v = conv_w[i];
        dst = ((l*HID + o)*2 + kk)*HID + ii;
    } else {
        v = proj_w[i - WS_CONV];
        dst = i;                         // proj [o][i] after conv region
    }
    const f16 hi = (f16)v;
    wh[dst]  = hi;
    wlo[dst] = (f16)((v - (float)hi) * SHI);
}

__global__ __launch_bounds__(1024, 4)
void wavenet5(const float* __restrict__ x,
              const f16*   __restrict__ wh,
              const f16*   __restrict__ wlo,
              const float* __restrict__ proj_b,
              const float* __restrict__ conv_b,
              const float* __restrict__ ev_w,
              const float* __restrict__ ev_b,
              const float* __restrict__ sw_w,
              const float* __restrict__ sw_b,
              float* __restrict__ out)
{
    extern __shared__ char ldsb[];
    f16*   Ht   = (f16*)ldsb;                       // hi  [128][264] swizzled
    f16*   Hl   = Ht + HT_HALFS;                    // lo'
    float* scr  = (float*)(ldsb + HT_HALFS*4);      // [8][132]
    float* attn = scr + 8*SCR_STRIDE;               // [128]
    float* redf = attn + TLEN;                      // [16]

    const int b    = blockIdx.x;
    const int tid  = threadIdx.x;
    const int lane = tid & 63;
    const int wv   = __builtin_amdgcn_readfirstlane(tid >> 6);  // 0..15
    const int mg   = wv & 7;           // o-tile: ob..ob+31
    const int ng   = wv >> 3;          // t-range: tb..tb+63 (2 n-tiles)
    const int ob   = mg << 5;
    const int tb   = ng << 6;
    const int col  = lane & 31;
    const int half = lane >> 5;

    f32x16 C[2], Cc[2];
    const f16x8 z8 = (f16x8)(f16)0.f;

    // ================= 1x1 projection 1024 -> 256 =================
    C[0] = (f32x16)0.f; C[1] = (f32x16)0.f; Cc[0] = (f32x16)0.f; Cc[1] = (f32x16)0.f;
    const f16* ph = wh  + WS_CONV;
    const f16* pl = wlo + WS_CONV;
    const float* xb = x + (size_t)b * INCH * TLEN;
    const int sr = tid >> 2, stq = tid & 3;   // stage: row in chunk, t-quarter
    float4 xv[8];
    {
        const float* xr = xb + (size_t)sr * TLEN + stq*32;
        #pragma unroll
        for (int u = 0; u < 8; ++u) xv[u] = *(const float4*)(xr + u*4);
    }
    #pragma unroll 1
    for (int c = 0; c < 4; ++c) {
        __syncthreads();           // previous chunk's B-reads complete
        #pragma unroll
        for (int u = 0; u < 8; ++u) {
            const float vv[4] = {xv[u].x, xv[u].y, xv[u].z, xv[u].w};
            #pragma unroll
            for (int e = 0; e < 4; ++e) {
                const int t = stq*32 + u*4 + e;
                const int p = t*HT_STRIDE + (((sr & ~7) ^ SW(t)) | (sr & 7));
                const f16 hi = (f16)vv[e];
                Ht[p] = hi;
                Hl[p] = (f16)((vv[e] - (float)hi) * SHI);
            }
        }
        __syncthreads();
        if (c < 3) {   // prefetch next chunk into registers during GEMM
            const float* xr = xb + (size_t)((c+1)*256 + sr) * TLEN + stq*32;
            #pragma unroll
            for (int u = 0; u < 8; ++u) xv[u] = *(const float4*)(xr + u*4);
        }
        #pragma unroll 4
        for (int ks = 0; ks < 16; ++ks) {
            const int kloc = ks*16 + half*8;
            const size_t ao = (size_t)(ob + col)*INCH + c*256 + kloc;
            const f16x8 Ah = *(const f16x8*)(ph + ao);
            const f16x8 Al = *(const f16x8*)(pl + ao);
            #pragma unroll
            for (int nt = 0; nt < 2; ++nt) {
                const int t = tb + nt*32 + col;
                const int bp = t*HT_STRIDE + (kloc ^ SW(t));
                const f16x8 Bh = *(const f16x8*)(Ht + bp);
                const f16x8 Bl = *(const f16x8*)(Hl + bp);
                C [nt] = MFMA32(Ah, Bh, C [nt]);
                Cc[nt] = MFMA32(Ah, Bl, Cc[nt]);
                Cc[nt] = MFMA32(Al, Bh, Cc[nt]);
            }
        }
    }
    __syncthreads();   // all B-reads done; Ht/Hl free for h
    #pragma unroll
    for (int nt = 0; nt < 2; ++nt) {
        const int t = tb + nt*32 + col;
        const int sw = SW(t);
        #pragma unroll
        for (int q = 0; q < 4; ++q) {
            const float4 bb = *(const float4*)(proj_b + ob + 8*q + 4*half);
            const float bv[4] = {bb.x, bb.y, bb.z, bb.w};
            f16x4 h4, l4;
            #pragma unroll
            for (int s = 0; s < 4; ++s) {
                const float v = C[nt][q*4+s] + Cc[nt][q*4+s]*SLO + bv[s];
                const f16 hi = (f16)v;
                h4[s] = hi; l4[s] = (f16)((v - (float)hi) * SHI);
            }
            const int p = t*HT_STRIDE + ((ob + 8*q) ^ sw) + 4*half;
            *(f16x4*)(Ht + p) = h4;
            *(f16x4*)(Hl + p) = l4;
        }
    }
    __syncthreads();

    // ================= 8 dilated residual layers =================
    const int DIL[NLAY] = {1, 2, 4, 8, 16, 32, 64, 1};
    #pragma unroll 1
    for (int l = 0; l < NLAY; ++l) {
        const int d = DIL[l];
        C[0] = (f32x16)0.f; C[1] = (f32x16)0.f; Cc[0] = (f32x16)0.f; Cc[1] = (f32x16)0.f;
        const f16* wA = wh  + (size_t)l*HID*2*HID;   // [o][kk][256]
        const f16* wL = wlo + (size_t)l*HID*2*HID;
        int  row1[2]; bool oob1[2];
        #pragma unroll
        for (int nt = 0; nt < 2; ++nt) {
            const int r = tb + nt*32 + col + d;
            oob1[nt] = r >= TLEN;
            row1[nt] = oob1[nt] ? TLEN-1 : r;
        }
        // ---- kk = 0 (no shift, no mask) ----
        #pragma unroll 4
        for (int ks = 0; ks < 16; ++ks) {
            const int kloc = ks*16 + half*8;
            const size_t ao = (size_t)((ob + col)*2 + 0)*HID + kloc;
            const f16x8 Ah = *(const f16x8*)(wA + ao);
            const f16x8 Al = *(const f16x8*)(wL + ao);
            #pragma unroll
            for (int nt = 0; nt < 2; ++nt) {
                const int t = tb + nt*32 + col;
                const int bp = t*HT_STRIDE + (kloc ^ SW(t));
                const f16x8 Bh = *(const f16x8*)(Ht + bp);
                const f16x8 Bl = *(const f16x8*)(Hl + bp);
                C [nt] = MFMA32(Ah, Bh, C [nt]);
                Cc[nt] = MFMA32(Ah, Bl, Cc[nt]);
                Cc[nt] = MFMA32(Al, Bh, Cc[nt]);
            }
        }
        // ---- kk = 1 (shift +d, boundary-masked) ----
        #pragma unroll 4
        for (int ks = 0; ks < 16; ++ks) {
            const int kloc = ks*16 + half*8;
            const size_t ao = (size_t)((ob + col)*2 + 1)*HID + kloc;
            const f16x8 Ah = *(const f16x8*)(wA + ao);
            const f16x8 Al = *(const f16x8*)(wL + ao);
            #pragma unroll
            for (int nt = 0; nt < 2; ++nt) {
                const int r = row1[nt];
                const int bp = r*HT_STRIDE + (kloc ^ SW(r));
                f16x8 Bh = *(const f16x8*)(Ht + bp);
                f16x8 Bl = *(const f16x8*)(Hl + bp);
                if (oob1[nt]) { Bh = z8; Bl = z8; }
                C [nt] = MFMA32(Ah, Bh, C [nt]);
                Cc[nt] = MFMA32(Ah, Bl, Cc[nt]);
                Cc[nt] = MFMA32(Al, Bh, Cc[nt]);
            }
        }
        // ---- epilogue: bias + leaky + skip + sumsq ----
        float ps[2] = {0.f, 0.f};
        #pragma unroll
        for (int nt = 0; nt < 2; ++nt) {
            const int t = tb + nt*32 + col;
            const int sw = SW(t);
            #pragma unroll
            for (int q = 0; q < 4; ++q) {
                const float4 bb = *(const float4*)(conv_b + l*HID + ob + 8*q + 4*half);
                const float bv[4] = {bb.x, bb.y, bb.z, bb.w};
                const int p = t*HT_STRIDE + ((ob + 8*q) ^ sw) + 4*half;
                const f16x4 sh = *(const f16x4*)(Ht + p);
                const f16x4 sl = *(const f16x4*)(Hl + p);
                #pragma unroll
                for (int s = 0; s < 4; ++s) {
                    float y = C[nt][q*4+s] + Cc[nt][q*4+s]*SLO + bv[s];
                    y = y > 0.f ? y : LEAKF * y;
                    const float v = y + (float)sh[s] + (float)sl[s]*SLO;
                    C[nt][q*4+s] = v;
                    ps[nt] = fmaf(v, v, ps[nt]);
                }
            }
        }
        ps[0] += __shfl_xor(ps[0], 32);
        ps[1] += __shfl_xor(ps[1], 32);
        if (lane < 32) {
            scr[mg*SCR_STRIDE + tb +      col] = ps[0];
            scr[mg*SCR_STRIDE + tb + 32 + col] = ps[1];
        }
        __syncthreads();   // all conv/skip reads done + scr complete
        float inv[2];
        #pragma unroll
        for (int nt = 0; nt < 2; ++nt) {
            const int t = tb + nt*32 + col;
            float s = 0.f;
            #pragma unroll
            for (int g = 0; g < 8; ++g) s += scr[g*SCR_STRIDE + t];
            inv[nt] = 1.f / (sqrtf(s) + EPSF);
        }
        #pragma unroll
        for (int nt = 0; nt < 2; ++nt) {
            const int t = tb + nt*32 + col;
            const int sw = SW(t);
            #pragma unroll
            for (int q = 0; q < 4; ++q) {
                f16x4 h4, l4;
                #pragma unroll
                for (int s = 0; s < 4; ++s) {
                    const float v = C[nt][q*4+s] * inv[nt];
                    const f16 hi = (f16)v;
                    h4[s] = hi; l4[s] = (f16)((v - (float)hi) * SHI);
                }
                const int p = t*HT_STRIDE + ((ob + 8*q) ^ sw) + 4*half;
                *(f16x4*)(Ht + p) = h4;
                *(f16x4*)(Hl + p) = l4;
            }
        }
        __syncthreads();
    }

    // ================= switch head -> relu -> argmax =================
    {
        const int t = tid & 127, og = tid >> 7;
        const int sw = SW(t);
        float s = 0.f;
        #pragma unroll
        for (int q = 0; q < 4; ++q) {
            const int grp = og*32 + q*8;
            const int p = t*HT_STRIDE + (grp ^ sw);
            const f16x8 hv = *(const f16x8*)(Ht + p);
            const f16x8 lv = *(const f16x8*)(Hl + p);
            const float* swp = sw_w + grp;
            #pragma unroll
            for (int j = 0; j < 8; ++j)
                s = fmaf(swp[j], (float)hv[j] + (float)lv[j]*SLO, s);
        }
        scr[og*SCR_STRIDE + t] = s;
    }
    __syncthreads();
    if (tid < TLEN) {
        float s = sw_b[0];
        #pragma unroll
        for (int g = 0; g < 8; ++g) s += scr[g*SCR_STRIDE + tid];
        attn[tid] = fmaxf(s, 0.f);
    }
    __syncthreads();
    if (tid < 64) {
        float v = attn[lane]; int bi = lane;
        const float v2 = attn[lane + 64];
        if (v2 > v) { v = v2; bi = lane + 64; }
        #pragma unroll
        for (int off = 32; off > 0; off >>= 1) {
            const float ov = __shfl_down(v, off);
            const int   oi = __shfl_down(bi, off);
            if (ov > v || (ov == v && oi < bi)) { v = ov; bi = oi; }
        }
        if (lane == 0) { redf[0] = v; ((int*)redf)[1] = bi; }
    }
    __syncthreads();
    const float bestv = redf[0];
    const int   bidx  = ((const int*)redf)[1];
    const int   swb   = SW(bidx);

    // event head: wave wv computes ctx=wv from h[:, bidx]
    {
        float s = 0.f;
        #pragma unroll
        for (int q = 0; q < 4; ++q) {
            const int o = lane + 64*q;
            const int p = bidx*HT_STRIDE + (((o & ~7) ^ swb) | (o & 7));
            const float hv = (float)Ht[p] + (float)Hl[p]*SLO;
            s = fmaf(ev_w[wv*HID + o], hv, s);
        }
        #pragma unroll
        for (int off = 32; off > 0; off >>= 1) s += __shfl_down(s, off);
        if (lane == 0) out[b*CTXN + wv] = s + ev_b[wv];
    }
    if (tid < TLEN) out[BATCH*CTXN + b*TLEN + tid] = (tid == bidx) ? bestv : 0.f;
}

extern "C" void kernel_launch(void* const* d_in, const int* in_sizes, int n_in,
                              void* d_out, int out_size, void* d_ws, size_t ws_size,
                              hipStream_t stream) {
    const float* x      = (const float*)d_in[0];
    const float* proj_w = (const float*)d_in[1];
    const float* proj_b = (const float*)d_in[2];
    const float* conv_w = (const float*)d_in[3];
    const float* conv_b = (const float*)d_in[4];
    const float* ev_w   = (const float*)d_in[5];
    const float* ev_b   = (const float*)d_in[6];
    const float* sw_w   = (const float*)d_in[7];
    const float* sw_b   = (const float*)d_in[8];
    float* out = (float*)d_out;

    f16* wh  = (f16*)d_ws;
    f16* wlo = wh + WS_TOT;

    prep_weights<<<(WS_TOT + 255)/256, 256, 0, stream>>>(conv_w, proj_w, wh, wlo);

    (void)hipFuncSetAttribute((const void*)wavenet5,
                              hipFuncAttributeMaxDynamicSharedMemorySize, (int)LDS_BYTES);
    wavenet5<<<BATCH, 1024, LDS_BYTES, stream>>>(x, wh, wlo, proj_b, conv_b,
                                                 ev_w, ev_b, sw_w, sw_b, out);
}